// Round 1
// baseline (3457.416 us; speedup 1.0000x reference)
//
#include <hip/hip_runtime.h>

#define N_TOK 131072
#define DIM   512
#define HID   512
#define NEXP  10

#define TM 64
#define BN 128
#define BK 32
#define APAD 4   // Ash stride 68 floats (272B, 16B-aligned, bank-shift 4)
#define HPAD 1   // hT stride 65 floats (2-way-max conflicts on write, none on read)

// ---------------- router: logits = x @ Wr^T + br, argmax ----------------
__global__ __launch_bounds__(256) void router_kernel(
    const float* __restrict__ x, const float* __restrict__ Wr,
    const float* __restrict__ br, int* __restrict__ eid,
    float* __restrict__ ids_out, int* __restrict__ counts)
{
    __shared__ float wr[NEXP][DIM];   // 20 KB
    __shared__ int lcnt[NEXP];
    int tid = threadIdx.x;
    for (int i = tid; i < NEXP * DIM / 4; i += 256)
        ((float4*)wr)[i] = ((const float4*)Wr)[i];
    if (tid < NEXP) lcnt[tid] = 0;
    __syncthreads();

    int lane  = tid & 63;
    int wave  = tid >> 6;
    int gwave = blockIdx.x * 4 + wave;
    int nwav  = gridDim.x * 4;

    for (int t = gwave; t < N_TOK; t += nwav) {
        const float4* xr = (const float4*)(x + (size_t)t * DIM);
        float4 v0 = xr[lane * 2], v1 = xr[lane * 2 + 1];
        float xf[8] = {v0.x, v0.y, v0.z, v0.w, v1.x, v1.y, v1.z, v1.w};
        float dot[NEXP];
        #pragma unroll
        for (int e = 0; e < NEXP; ++e) {
            const float* w = &wr[e][lane * 8];
            float s = 0.f;
            #pragma unroll
            for (int j = 0; j < 8; ++j) s = fmaf(xf[j], w[j], s);
            dot[e] = s;
        }
        #pragma unroll
        for (int off = 32; off > 0; off >>= 1) {
            #pragma unroll
            for (int e = 0; e < NEXP; ++e) dot[e] += __shfl_xor(dot[e], off, 64);
        }
        if (lane == 0) {
            int best = 0; float bv = dot[0] + br[0];
            #pragma unroll
            for (int e = 1; e < NEXP; ++e) {
                float v = dot[e] + br[e];
                if (v > bv) { bv = v; best = e; }
            }
            eid[t] = best;
            ids_out[t] = (float)best;
            atomicAdd(&lcnt[best], 1);
        }
    }
    __syncthreads();
    if (tid < NEXP) atomicAdd(&counts[tid], lcnt[tid]);
}

// ---------------- prefix sum over 10 counts ----------------
__global__ void offsets_kernel(const int* __restrict__ counts, int* __restrict__ offsets)
{
    if (threadIdx.x == 0) {
        int acc = 0;
        for (int e = 0; e < NEXP; ++e) { offsets[e] = acc; acc += counts[e]; }
        offsets[NEXP] = acc;
    }
}

// ---------------- bucket scatter: perm[offset[e] + pos] = token ----------------
__global__ __launch_bounds__(256) void scatter_kernel(
    const int* __restrict__ eid, const int* __restrict__ offsets,
    int* __restrict__ cursors, int* __restrict__ perm)
{
    __shared__ int lcnt[NEXP], lbase[NEXP];
    int tid = threadIdx.x;
    if (tid < NEXP) lcnt[tid] = 0;
    __syncthreads();
    int t = blockIdx.x * 256 + tid;
    int e = 0, lpos = 0;
    if (t < N_TOK) {
        e = eid[t];
        lpos = atomicAdd(&lcnt[e], 1);
    }
    __syncthreads();
    if (tid < NEXP) lbase[tid] = atomicAdd(&cursors[tid], lcnt[tid]);
    __syncthreads();
    if (t < N_TOK) perm[offsets[e] + lbase[e] + lpos] = t;
}

// ---------------- fused 2-layer expert FFN over one 64-token tile ----------------
__global__ __launch_bounds__(256) void expert_kernel(
    const float* __restrict__ x,
    const float* __restrict__ W1, const float* __restrict__ b1,
    const float* __restrict__ W2, const float* __restrict__ b2,
    const int* __restrict__ offsets, const int* __restrict__ perm,
    float* __restrict__ out)
{
    int e    = blockIdx.y;
    int beg  = offsets[e], end = offsets[e + 1];
    int cnt  = end - beg;
    int m0   = blockIdx.x * TM;
    if (m0 >= cnt) return;
    int mval = min(TM, cnt - m0);

    __shared__ int   toks[TM];
    __shared__ float Ash[BK][TM + APAD];   // 8704 B
    __shared__ float Bsh[BK][BN];          // 16384 B
    __shared__ float hT[HID][TM + HPAD];   // 133120 B (transposed h for layer-2 A)

    int tid = threadIdx.x;
    int tx  = tid & 15;     // 16 col-groups
    int ty  = tid >> 4;     // 16 row-groups

    if (tid < TM) {
        int idx = m0 + tid;
        toks[tid] = perm[beg + (idx < cnt ? idx : cnt - 1)];
    }
    __syncthreads();

    const float* W1e = W1 + (size_t)e * DIM * HID;
    const float* W2e = W2 + (size_t)e * HID * HID;
    const float* b1e = b1 + (size_t)e * HID;
    const float* b2e = b2 + (size_t)e * HID;

    // ======== layer 1: hT = relu(x[toks] @ W1e + b1e), stored transposed ========
    for (int hc = 0; hc < HID; hc += BN) {
        float acc[4][8];
        #pragma unroll
        for (int r = 0; r < 4; ++r)
            #pragma unroll
            for (int c = 0; c < 8; ++c) acc[r][c] = 0.f;

        for (int k0 = 0; k0 < DIM; k0 += BK) {
            __syncthreads();
            // stage A (gathered x rows, transposed): 64x32 floats = 512 float4
            #pragma unroll
            for (int i = 0; i < 2; ++i) {
                int id  = i * 256 + tid;
                int row = id >> 3;            // 0..63
                int c4  = (id & 7) * 4;       // 0..28
                float4 v = *(const float4*)(x + (size_t)toks[row] * DIM + k0 + c4);
                Ash[c4 + 0][row] = v.x; Ash[c4 + 1][row] = v.y;
                Ash[c4 + 2][row] = v.z; Ash[c4 + 3][row] = v.w;
            }
            // stage B: W1e rows k0..k0+31, cols hc..hc+127 (1024 float4)
            #pragma unroll
            for (int i = 0; i < 4; ++i) {
                int id  = i * 256 + tid;
                int row = id >> 5;            // 0..31
                int c4  = (id & 31) * 4;      // 0..124
                *(float4*)&Bsh[row][c4] =
                    *(const float4*)(W1e + (size_t)(k0 + row) * HID + hc + c4);
            }
            __syncthreads();
            #pragma unroll
            for (int kk = 0; kk < BK; ++kk) {
                float4 a  = *(const float4*)&Ash[kk][ty * 4];
                float4 b0 = *(const float4*)&Bsh[kk][tx * 4];
                float4 b1v = *(const float4*)&Bsh[kk][64 + tx * 4];
                float av[4] = {a.x, a.y, a.z, a.w};
                float bv[8] = {b0.x, b0.y, b0.z, b0.w, b1v.x, b1v.y, b1v.z, b1v.w};
                #pragma unroll
                for (int r = 0; r < 4; ++r)
                    #pragma unroll
                    for (int c = 0; c < 8; ++c)
                        acc[r][c] = fmaf(av[r], bv[c], acc[r][c]);
            }
        }
        // epilogue: bias + relu, store transposed into hT
        #pragma unroll
        for (int c = 0; c < 4; ++c) {
            int col0 = hc + tx * 4 + c;
            int col1 = hc + 64 + tx * 4 + c;
            float bb0 = b1e[col0], bb1 = b1e[col1];
            #pragma unroll
            for (int r = 0; r < 4; ++r) {
                float v0 = acc[r][c] + bb0;
                float v1 = acc[r][4 + c] + bb1;
                hT[col0][ty * 4 + r] = v0 > 0.f ? v0 : 0.f;
                hT[col1][ty * 4 + r] = v1 > 0.f ? v1 : 0.f;
            }
        }
    }
    __syncthreads();   // hT complete before layer 2 reads

    // ======== layer 2: out[toks] = hT^T @ W2e + b2e ========
    for (int oc = 0; oc < HID; oc += BN) {
        float acc[4][8];
        #pragma unroll
        for (int r = 0; r < 4; ++r)
            #pragma unroll
            for (int c = 0; c < 8; ++c) acc[r][c] = 0.f;

        for (int k0 = 0; k0 < HID; k0 += BK) {
            __syncthreads();
            #pragma unroll
            for (int i = 0; i < 4; ++i) {
                int id  = i * 256 + tid;
                int row = id >> 5;
                int c4  = (id & 31) * 4;
                *(float4*)&Bsh[row][c4] =
                    *(const float4*)(W2e + (size_t)(k0 + row) * HID + oc + c4);
            }
            __syncthreads();
            #pragma unroll
            for (int kk = 0; kk < BK; ++kk) {
                int k = k0 + kk;
                float av[4];
                #pragma unroll
                for (int r = 0; r < 4; ++r) av[r] = hT[k][ty * 4 + r];
                float4 b0 = *(const float4*)&Bsh[kk][tx * 4];
                float4 b1v = *(const float4*)&Bsh[kk][64 + tx * 4];
                float bv[8] = {b0.x, b0.y, b0.z, b0.w, b1v.x, b1v.y, b1v.z, b1v.w};
                #pragma unroll
                for (int r = 0; r < 4; ++r)
                    #pragma unroll
                    for (int c = 0; c < 8; ++c)
                        acc[r][c] = fmaf(av[r], bv[c], acc[r][c]);
            }
        }
        // epilogue: bias, coalesced float4 stores to gathered rows
        #pragma unroll
        for (int r = 0; r < 4; ++r) {
            int m = ty * 4 + r;
            if (m < mval) {
                int tok = toks[m];
                float4 v, w;
                v.x = acc[r][0] + b2e[oc + tx * 4 + 0];
                v.y = acc[r][1] + b2e[oc + tx * 4 + 1];
                v.z = acc[r][2] + b2e[oc + tx * 4 + 2];
                v.w = acc[r][3] + b2e[oc + tx * 4 + 3];
                w.x = acc[r][4] + b2e[oc + 64 + tx * 4 + 0];
                w.y = acc[r][5] + b2e[oc + 64 + tx * 4 + 1];
                w.z = acc[r][6] + b2e[oc + 64 + tx * 4 + 2];
                w.w = acc[r][7] + b2e[oc + 64 + tx * 4 + 3];
                *(float4*)(out + (size_t)tok * HID + oc + tx * 4) = v;
                *(float4*)(out + (size_t)tok * HID + oc + 64 + tx * 4) = w;
            }
        }
    }
}

extern "C" void kernel_launch(void* const* d_in, const int* in_sizes, int n_in,
                              void* d_out, int out_size, void* d_ws, size_t ws_size,
                              hipStream_t stream)
{
    const float* x  = (const float*)d_in[0];
    const float* Wr = (const float*)d_in[1];
    const float* br = (const float*)d_in[2];
    const float* W1 = (const float*)d_in[3];
    const float* b1 = (const float*)d_in[4];
    const float* W2 = (const float*)d_in[5];
    const float* b2 = (const float*)d_in[6];

    float* out     = (float*)d_out;
    float* ids_out = out + (size_t)N_TOK * HID;

    int* counts  = (int*)d_ws;          // [0..15]
    int* offsets = counts + 16;         // [16..31] (uses 11)
    int* cursors = counts + 32;         // [32..47]
    int* eid     = (int*)((char*)d_ws + 1024);
    int* perm    = eid + N_TOK;

    hipMemsetAsync(d_ws, 0, 1024, stream);
    router_kernel<<<2048, 256, 0, stream>>>(x, Wr, br, eid, ids_out, counts);
    offsets_kernel<<<1, 64, 0, stream>>>(counts, offsets);
    scatter_kernel<<<512, 256, 0, stream>>>(eid, offsets, cursors, perm);
    expert_kernel<<<dim3(2048, NEXP), 256, 0, stream>>>(
        x, W1, b1, W2, b2, offsets, perm, out);
}

// Round 2
// 434.017 us; speedup vs baseline: 7.9661x; 7.9661x over previous
//
#include <hip/hip_runtime.h>

#define N_TOK 131072
#define DIM   512
#define HID   512
#define NEXP  10

using bf16x8 = __attribute__((ext_vector_type(8))) short;
using f32x4  = __attribute__((ext_vector_type(4))) float;

__device__ __forceinline__ ushort f2bf(float f) {
    union { float f; unsigned u; } v; v.f = f;
    unsigned u = v.u;
    return (ushort)((u + 0x7FFFu + ((u >> 16) & 1u)) >> 16);   // RNE
}

#define GLOAD16(g, l) __builtin_amdgcn_global_load_lds( \
    (const __attribute__((address_space(1))) void*)(g),  \
    (__attribute__((address_space(3))) void*)(l), 16, 0, 0)

// ---------------- router: logits = x @ Wr^T + br, argmax ----------------
__global__ __launch_bounds__(256) void router_kernel(
    const float* __restrict__ x, const float* __restrict__ Wr,
    const float* __restrict__ br, int* __restrict__ eid,
    float* __restrict__ ids_out, int* __restrict__ counts)
{
    __shared__ float wr[NEXP][DIM];
    __shared__ int lcnt[NEXP];
    int tid = threadIdx.x;
    for (int i = tid; i < NEXP * DIM / 4; i += 256)
        ((float4*)wr)[i] = ((const float4*)Wr)[i];
    if (tid < NEXP) lcnt[tid] = 0;
    __syncthreads();

    int lane  = tid & 63;
    int wave  = tid >> 6;
    int gwave = blockIdx.x * 4 + wave;
    int nwav  = gridDim.x * 4;

    for (int t = gwave; t < N_TOK; t += nwav) {
        const float4* xr = (const float4*)(x + (size_t)t * DIM);
        float4 v0 = xr[lane * 2], v1 = xr[lane * 2 + 1];
        float xf[8] = {v0.x, v0.y, v0.z, v0.w, v1.x, v1.y, v1.z, v1.w};
        float dot[NEXP];
        #pragma unroll
        for (int e = 0; e < NEXP; ++e) {
            const float* wv = &wr[e][lane * 8];
            float s = 0.f;
            #pragma unroll
            for (int j = 0; j < 8; ++j) s = fmaf(xf[j], wv[j], s);
            dot[e] = s;
        }
        #pragma unroll
        for (int off = 32; off > 0; off >>= 1) {
            #pragma unroll
            for (int e = 0; e < NEXP; ++e) dot[e] += __shfl_xor(dot[e], off, 64);
        }
        if (lane == 0) {
            int best = 0; float bv = dot[0] + br[0];
            #pragma unroll
            for (int e = 1; e < NEXP; ++e) {
                float v = dot[e] + br[e];
                if (v > bv) { bv = v; best = e; }
            }
            eid[t] = best;
            ids_out[t] = (float)best;
            atomicAdd(&lcnt[best], 1);
        }
    }
    __syncthreads();
    if (tid < NEXP) atomicAdd(&counts[tid], lcnt[tid]);
}

// ---------------- prefix sums: token offsets + tile offsets ----------------
__global__ void offsets_kernel(const int* __restrict__ counts,
                               int* __restrict__ offsets, int* __restrict__ toff)
{
    if (threadIdx.x == 0) {
        int acc = 0, ta = 0;
        for (int e = 0; e < NEXP; ++e) {
            offsets[e] = acc; toff[e] = ta;
            acc += counts[e]; ta += (counts[e] + 63) >> 6;
        }
        offsets[NEXP] = acc; toff[NEXP] = ta;
    }
}

// ---------------- bucket scatter: perm[offset[e] + pos] = token ----------------
__global__ __launch_bounds__(256) void scatter_kernel(
    const int* __restrict__ eid, const int* __restrict__ offsets,
    int* __restrict__ cursors, int* __restrict__ perm)
{
    __shared__ int lcnt[NEXP], lbase[NEXP];
    int tid = threadIdx.x;
    if (tid < NEXP) lcnt[tid] = 0;
    __syncthreads();
    int t = blockIdx.x * 256 + tid;
    int e = 0, lpos = 0;
    if (t < N_TOK) {
        e = eid[t];
        lpos = atomicAdd(&lcnt[e], 1);
    }
    __syncthreads();
    if (tid < NEXP) lbase[tid] = atomicAdd(&cursors[tid], lcnt[tid]);
    __syncthreads();
    if (t < N_TOK) perm[offsets[e] + lbase[e] + lpos] = t;
}

// ---------------- transpose-convert weights: [512][512] f32 -> [n][k] bf16 ----------------
__global__ __launch_bounds__(256) void wconvert_kernel(
    const float* __restrict__ W1, const float* __restrict__ W2,
    short* __restrict__ W1bT, short* __restrict__ W2bT)
{
    int mat = blockIdx.z;
    const float* src = (mat < NEXP) ? W1 + (size_t)mat * 512 * 512
                                    : W2 + (size_t)(mat - NEXP) * 512 * 512;
    short* dst = (mat < NEXP) ? W1bT + (size_t)mat * 512 * 512
                              : W2bT + (size_t)(mat - NEXP) * 512 * 512;
    __shared__ float tile[64][65];
    int r0 = blockIdx.y * 64, c0 = blockIdx.x * 64;
    int tid = threadIdx.x;
    int tr = tid >> 4, tc4 = (tid & 15) * 4;
    #pragma unroll
    for (int i = 0; i < 4; ++i) {
        float4 v = *(const float4*)(src + (size_t)(r0 + i * 16 + tr) * 512 + c0 + tc4);
        tile[i * 16 + tr][tc4 + 0] = v.x; tile[i * 16 + tr][tc4 + 1] = v.y;
        tile[i * 16 + tr][tc4 + 2] = v.z; tile[i * 16 + tr][tc4 + 3] = v.w;
    }
    __syncthreads();
    #pragma unroll
    for (int i = 0; i < 4; ++i) {
        int cc = i * 16 + tr;           // output row (= source col)
        ushort4 o;
        o.x = f2bf(tile[tc4 + 0][cc]); o.y = f2bf(tile[tc4 + 1][cc]);
        o.z = f2bf(tile[tc4 + 2][cc]); o.w = f2bf(tile[tc4 + 3][cc]);
        *(ushort4*)(dst + (size_t)(c0 + cc) * 512 + r0 + tc4) = o;
    }
}

// ---------------- MFMA expert GEMM: tile 64 rows x 512 cols, K=512 ----------------
// LAYER==1: A = gathered x rows (fp32 -> bf16 reg-stage), out = relu(.+b1) -> h (bf16)
// LAYER==2: A = packed h rows (bf16 via global_load_lds), out = . + b2 -> out[tok] (f32)
template<int LAYER>
__global__ __launch_bounds__(256, 2) void expert_gemm(
    const float* __restrict__ x, const short* __restrict__ hA,
    const short* __restrict__ WT, const float* __restrict__ bias,
    const int* __restrict__ offsets, const int* __restrict__ toff,
    const int* __restrict__ perm,
    short* __restrict__ hOut, float* __restrict__ out)
{
    int g = blockIdx.x;
    if (g >= toff[NEXP]) return;
    int e = 0;
    #pragma unroll
    for (int k = 1; k < NEXP; ++k) e += (g >= toff[k]);
    int beg = offsets[e], cnt = offsets[e + 1] - beg;
    int m0 = (g - toff[e]) * 64;

    __shared__ int toks[64];
    __shared__ short Abuf[2][64 * 32];     // [row][k] bf16, 4 KB each
    __shared__ short Bbuf[2][512 * 32];    // [n][k]   bf16, 32 KB each

    int tid = threadIdx.x, lane = tid & 63, w = tid >> 6;
    if (tid < 64) toks[tid] = perm[beg + min(m0 + tid, cnt - 1)];
    __syncthreads();

    int srow = tid >> 2;        // A-tile row this thread stages
    int skq  = tid & 3;         // 16B quarter within the 64B k-row
    const float* asrcF = nullptr;
    const short* asrcH = nullptr;
    if (LAYER == 1) asrcF = x + (size_t)toks[srow] * DIM + skq * 8;
    else            asrcH = hA + (size_t)(beg + min(m0 + srow, cnt - 1)) * HID + skq * 8;
    const short* bsrc = WT + (size_t)e * 512 * 512 + (size_t)srow * 512 + skq * 8;

    auto stage = [&](int t, int b) {
        float4 a0, a1;
        if (LAYER == 1) {
            a0 = *(const float4*)(asrcF + t * 32);
            a1 = *(const float4*)(asrcF + t * 32 + 4);
        } else {
            GLOAD16(asrcH + t * 32, (char*)&Abuf[b][0] + w * 1024);
        }
        const short* bs = bsrc + t * 32;
        char* bl = (char*)&Bbuf[b][0] + w * 1024;
        #pragma unroll
        for (int r = 0; r < 8; ++r)
            GLOAD16(bs + (size_t)r * 64 * 512, bl + r * 4096);
        if (LAYER == 1) {
            bf16x8 ap;
            ap[0] = (short)f2bf(a0.x); ap[1] = (short)f2bf(a0.y);
            ap[2] = (short)f2bf(a0.z); ap[3] = (short)f2bf(a0.w);
            ap[4] = (short)f2bf(a1.x); ap[5] = (short)f2bf(a1.y);
            ap[6] = (short)f2bf(a1.z); ap[7] = (short)f2bf(a1.w);
            *(bf16x8*)((char*)&Abuf[b][0] + srow * 64 + skq * 16) = ap;
        }
    };

    f32x4 acc[4][8];
    #pragma unroll
    for (int i = 0; i < 4; ++i)
        #pragma unroll
        for (int j = 0; j < 8; ++j) acc[i][j] = (f32x4){0.f, 0.f, 0.f, 0.f};

    int lrow = lane & 15;
    int lk   = (lane >> 4) * 8;

    auto compute = [&](int b) {
        const short* A = &Abuf[b][0];
        const short* B = &Bbuf[b][0];
        bf16x8 af[4], bfv[8];
        #pragma unroll
        for (int i = 0; i < 4; ++i)
            af[i] = *(const bf16x8*)(A + (i * 16 + lrow) * 32 + lk);
        #pragma unroll
        for (int j = 0; j < 8; ++j)
            bfv[j] = *(const bf16x8*)(B + (w * 128 + j * 16 + lrow) * 32 + lk);
        #pragma unroll
        for (int i = 0; i < 4; ++i)
            #pragma unroll
            for (int j = 0; j < 8; ++j)
                acc[i][j] = __builtin_amdgcn_mfma_f32_16x16x32_bf16(af[i], bfv[j], acc[i][j], 0, 0, 0);
    };

    stage(0, 0);
    __syncthreads();
    #pragma unroll 1
    for (int t = 0; t < 14; t += 2) {
        stage(t + 1, 1); compute(0); __syncthreads();
        stage(t + 2, 0); compute(1); __syncthreads();
    }
    stage(15, 1); compute(0); __syncthreads();
    compute(1);

    // ---- epilogue ----
    const float* be = bias + (size_t)e * 512;
    int colb = w * 128 + lrow;
    float bv[8];
    #pragma unroll
    for (int j = 0; j < 8; ++j) bv[j] = be[colb + j * 16];

    #pragma unroll
    for (int i = 0; i < 4; ++i) {
        #pragma unroll
        for (int q = 0; q < 4; ++q) {
            int rr = i * 16 + ((lane >> 4) << 2) + q;
            if (m0 + rr < cnt) {
                if (LAYER == 1) {
                    short* hp = hOut + (size_t)(beg + m0 + rr) * HID + colb;
                    #pragma unroll
                    for (int j = 0; j < 8; ++j) {
                        float v = acc[i][j][q] + bv[j];
                        hp[j * 16] = (short)f2bf(v > 0.f ? v : 0.f);
                    }
                } else {
                    float* op = out + (size_t)toks[rr] * HID + colb;
                    #pragma unroll
                    for (int j = 0; j < 8; ++j)
                        op[j * 16] = acc[i][j][q] + bv[j];
                }
            }
        }
    }
}

extern "C" void kernel_launch(void* const* d_in, const int* in_sizes, int n_in,
                              void* d_out, int out_size, void* d_ws, size_t ws_size,
                              hipStream_t stream)
{
    const float* x  = (const float*)d_in[0];
    const float* Wr = (const float*)d_in[1];
    const float* br = (const float*)d_in[2];
    const float* W1 = (const float*)d_in[3];
    const float* b1 = (const float*)d_in[4];
    const float* W2 = (const float*)d_in[5];
    const float* b2 = (const float*)d_in[6];

    float* out     = (float*)d_out;
    float* ids_out = out + (size_t)N_TOK * HID;

    char* ws     = (char*)d_ws;
    int* counts  = (int*)ws;            // 16 ints
    int* offsets = counts + 16;         // 11 used
    int* toff    = counts + 32;         // 11 used
    int* cursors = counts + 48;         // 16
    int* eid     = (int*)(ws + 1024);
    int* perm    = eid + N_TOK;
    short* W1bT  = (short*)(ws + 1024 + (size_t)2 * N_TOK * 4);
    short* W2bT  = W1bT + (size_t)NEXP * 512 * 512;
    short* h     = W2bT + (size_t)NEXP * 512 * 512;

    hipMemsetAsync(d_ws, 0, 1024, stream);
    router_kernel<<<2048, 256, 0, stream>>>(x, Wr, br, eid, ids_out, counts);
    wconvert_kernel<<<dim3(8, 8, 2 * NEXP), 256, 0, stream>>>(W1, W2, W1bT, W2bT);
    offsets_kernel<<<1, 64, 0, stream>>>(counts, offsets, toff);
    scatter_kernel<<<512, 256, 0, stream>>>(eid, offsets, cursors, perm);

    int ntiles = (N_TOK + 63) / 64 + NEXP;   // upper bound on total tiles
    expert_gemm<1><<<ntiles, 256, 0, stream>>>(x, nullptr, W1bT, b1, offsets, toff, perm, h, nullptr);
    expert_gemm<2><<<ntiles, 256, 0, stream>>>(nullptr, h, W2bT, b2, offsets, toff, perm, nullptr, out);
}